// Round 5
// baseline (238.440 us; speedup 1.0000x reference)
//
#include <hip/hip_runtime.h>
#include <math.h>

// Problem constants (SHAPE = (1, 128, 48, 48, 48), FILTERS = (1,3,3,3,1))
#define NCH      128
#define SPATIAL  110592            // 48*48*48
#define NV4      3538944           // NCH*SPATIAL/4 total float4 groups
#define CV4      27648             // SPATIAL/4 float4 groups per channel
#define THREADS  256
#define GRID     1728              // GRID*THREADS*8 == NV4 exactly; stride = 16*CV4
#define KTILES   8
#define STRIDE   442368            // GRID*THREADS (v4f units) == 16*CV4

#define QT 21.416413017506358f     // log(2/1e-9 - 1)

typedef float v4f __attribute__((ext_vector_type(4)));

__device__ __forceinline__ float frcp(float x){ return __builtin_amdgcn_rcpf(x); }
__device__ __forceinline__ float ftanh(float x){ return 1.0f - 2.0f*frcp(__expf(2.0f*x) + 1.0f); }
__device__ __forceinline__ float fsig(float x){ return frcp(1.0f + __expf(-x)); }
__device__ __forceinline__ float fsoftplus(float x){ return fmaxf(x, 0.0f) + log1pf(__expf(-fabsf(x))); }

struct Params {
    float w0[3], w1[9], w2[9], w3[3];
    float t0[3], t1[3], t2[3];
    float B0[3], B1[3], B2[3], B3;
};

__device__ __forceinline__ Params load_params(int c,
    const float* __restrict__ m0, const float* __restrict__ b0, const float* __restrict__ f0,
    const float* __restrict__ m1, const float* __restrict__ b1, const float* __restrict__ f1,
    const float* __restrict__ m2, const float* __restrict__ b2, const float* __restrict__ f2,
    const float* __restrict__ m3, const float* __restrict__ b3)
{
    Params P;
    #pragma unroll
    for (int k=0;k<3;k++) P.w0[k]=fsoftplus(m0[c*3+k]);
    #pragma unroll
    for (int k=0;k<9;k++) P.w1[k]=fsoftplus(m1[c*9+k]);
    #pragma unroll
    for (int k=0;k<9;k++) P.w2[k]=fsoftplus(m2[c*9+k]);
    #pragma unroll
    for (int k=0;k<3;k++) P.w3[k]=fsoftplus(m3[c*3+k]);
    #pragma unroll
    for (int k=0;k<3;k++) P.t0[k]=ftanh(f0[c*3+k]);
    #pragma unroll
    for (int k=0;k<3;k++) P.t1[k]=ftanh(f1[c*3+k]);
    #pragma unroll
    for (int k=0;k<3;k++) P.t2[k]=ftanh(f2[c*3+k]);
    #pragma unroll
    for (int k=0;k<3;k++) P.B0[k]=b0[c*3+k];
    #pragma unroll
    for (int k=0;k<3;k++) P.B1[k]=b1[c*3+k];
    #pragma unroll
    for (int k=0;k<3;k++) P.B2[k]=b2[c*3+k];
    P.B3 = b3[c];
    return P;
}

template<bool USE_F>
__device__ __forceinline__ float eval_mlp(float z, const Params& P){
    float h0 = fmaf(P.w0[0], z, P.B0[0]);
    float h1 = fmaf(P.w0[1], z, P.B0[1]);
    float h2 = fmaf(P.w0[2], z, P.B0[2]);
    if (USE_F){
        h0 = fmaf(P.t0[0], ftanh(h0), h0);
        h1 = fmaf(P.t0[1], ftanh(h1), h1);
        h2 = fmaf(P.t0[2], ftanh(h2), h2);
    }
    float g0 = fmaf(P.w1[0],h0, fmaf(P.w1[1],h1, fmaf(P.w1[2],h2, P.B1[0])));
    float g1 = fmaf(P.w1[3],h0, fmaf(P.w1[4],h1, fmaf(P.w1[5],h2, P.B1[1])));
    float g2 = fmaf(P.w1[6],h0, fmaf(P.w1[7],h1, fmaf(P.w1[8],h2, P.B1[2])));
    if (USE_F){
        g0 = fmaf(P.t1[0], ftanh(g0), g0);
        g1 = fmaf(P.t1[1], ftanh(g1), g1);
        g2 = fmaf(P.t1[2], ftanh(g2), g2);
    }
    h0 = fmaf(P.w2[0],g0, fmaf(P.w2[1],g1, fmaf(P.w2[2],g2, P.B2[0])));
    h1 = fmaf(P.w2[3],g0, fmaf(P.w2[4],g1, fmaf(P.w2[5],g2, P.B2[1])));
    h2 = fmaf(P.w2[6],g0, fmaf(P.w2[7],g1, fmaf(P.w2[8],g2, P.B2[2])));
    if (USE_F){
        h0 = fmaf(P.t2[0], ftanh(h0), h0);
        h1 = fmaf(P.t2[1], ftanh(h1), h1);
        h2 = fmaf(P.t2[2], ftanh(h2), h2);
    }
    return fmaf(P.w3[0],h0, fmaf(P.w3[1],h1, fmaf(P.w3[2],h2, P.B3)));
}

__device__ __forceinline__ float lik_from_logits(float lo, float hi){
    float su = lo + hi;
    float s  = (su > 0.0f) ? -1.0f : ((su < 0.0f) ? 1.0f : 0.0f);   // -sign(lo+hi)
    float a  = fsig(s*hi);
    float b  = fsig(s*lo);
    return fmaxf(fabsf(a - b), 1e-9f);        // LIKELIHOOD_BOUND
}

// ---------------------------------------------------------------------------
// Prep kernel (1 block, 384 threads): quantiles_loss, per-channel linear
// collapse (A, Bl) -> ws, and the use_f flag -> ws.
// ---------------------------------------------------------------------------
__global__ __launch_bounds__(384) void eb_prep(
    const float* __restrict__ m0, const float* __restrict__ b0, const float* __restrict__ f0,
    const float* __restrict__ m1, const float* __restrict__ b1, const float* __restrict__ f1,
    const float* __restrict__ m2, const float* __restrict__ b2, const float* __restrict__ f2,
    const float* __restrict__ m3, const float* __restrict__ b3,
    const float* __restrict__ q, float* __restrict__ loss,
    float2* __restrict__ ab, int* __restrict__ flag)
{
    const int tid = threadIdx.x;
    const int c = tid / 3;
    const int j = tid - c*3;

    Params P = load_params(c, m0,b0,f0, m1,b1,f1, m2,b2,f2, m3,b3);

    bool anyf = false;
    #pragma unroll
    for (int k=0;k<3;k++)
        anyf = anyf || (P.t0[k]!=0.0f) || (P.t1[k]!=0.0f) || (P.t2[k]!=0.0f);

    __shared__ int sf;
    if (tid == 0) sf = 0;
    __syncthreads();
    if (anyf) sf = 1;                        // benign race: all writers store 1

    float z      = q[c*3 + j];
    float logit  = eval_mlp<true>(z, P);
    float target = (j==0) ? -QT : ((j==1) ? 0.0f : QT);
    float diff   = fabsf(logit - target);

    #pragma unroll
    for (int off = 32; off > 0; off >>= 1)
        diff += __shfl_down(diff, off, 64);

    __shared__ float red[6];
    if ((tid & 63) == 0) red[tid >> 6] = diff;
    __syncthreads();                         // publishes red[] and sf
    if (tid == 0){
        float s = 0.0f;
        #pragma unroll
        for (int i = 0; i < 6; i++) s += red[i];
        *loss = s;
        *flag = sf;
    }

    if (j == 0){                             // one thread per channel
        float B = eval_mlp<false>(0.0f, P);
        float A = eval_mlp<false>(1.0f, P) - B;
        ab[c] = make_float2(A, B - 0.5f*A);  // Bl = B - A/2
    }
}

// ---------------------------------------------------------------------------
// Main kernel: 8 tiles/thread, exact partition (no bounds checks), all 16
// input loads batch-issued (progressive vmcnt drain), channel set is
// block-uniform: c_k = blockIdx.x/108 + 16k. No LDS, no divs in hot path.
// ---------------------------------------------------------------------------
__global__ __launch_bounds__(THREADS) void eb_main(
    const float* __restrict__ x, const float* __restrict__ noise,
    const float* __restrict__ m0, const float* __restrict__ b0, const float* __restrict__ f0,
    const float* __restrict__ m1, const float* __restrict__ b1, const float* __restrict__ f1,
    const float* __restrict__ m2, const float* __restrict__ b2, const float* __restrict__ f2,
    const float* __restrict__ m3, const float* __restrict__ b3,
    const float2* __restrict__ ab, const int* __restrict__ flag,
    float* __restrict__ out, float* __restrict__ lik)
{
    const int tid   = threadIdx.x;
    const int cbase = blockIdx.x / 108;      // 27648/256: uniform channel base
    const int i0    = blockIdx.x*THREADS + tid;

    const v4f* __restrict__ x4 = (const v4f*)x;
    const v4f* __restrict__ n4 = (const v4f*)noise;
    v4f* __restrict__ o4 = (v4f*)out;
    v4f* __restrict__ l4 = (v4f*)lik;

    const bool use_f = (*flag != 0);

    if (!use_f){
        // per-tile linear params (uniform within block)
        float A[KTILES], Bl[KTILES];
        #pragma unroll
        for (int k = 0; k < KTILES; ++k){
            float2 v = ab[cbase + 16*k];
            A[k] = v.x; Bl[k] = v.y;
        }

        // batch-issue ALL input loads, x/n interleaved so tile k's pair
        // completes at vmcnt(14-2k) -- progressive drain, no full stall
        v4f xv[KTILES], nv[KTILES];
        #pragma unroll
        for (int k = 0; k < KTILES; ++k){
            xv[k] = x4[i0 + k*STRIDE];
            nv[k] = n4[i0 + k*STRIDE];
        }

        #pragma unroll
        for (int k = 0; k < KTILES; ++k){
            v4f ov, lv;
            #pragma unroll
            for (int e = 0; e < 4; ++e){
                float o  = xv[k][e] + nv[k][e] - 0.5f;
                float lo = fmaf(A[k], o, Bl[k]);   // logit(o-0.5)
                float hi = lo + A[k];              // logit(o+0.5)
                ov[e] = o;
                lv[e] = lik_from_logits(lo, hi);
            }
            __builtin_nontemporal_store(ov, o4 + i0 + k*STRIDE);
            __builtin_nontemporal_store(lv, l4 + i0 + k*STRIDE);
        }
    } else {
        // General path (nonzero factors): correct, params via L1/L2.
        #pragma unroll
        for (int k = 0; k < KTILES; ++k){
            const int i = i0 + k*STRIDE;
            const int c = cbase + 16*k;
            Params P = load_params(c, m0,b0,f0, m1,b1,f1, m2,b2,f2, m3,b3);
            v4f xvv = x4[i], nvv = n4[i];
            v4f ov, lv;
            #pragma unroll
            for (int e = 0; e < 4; ++e){
                float o  = xvv[e] + nvv[e] - 0.5f;
                float lo = eval_mlp<true>(o - 0.5f, P);
                float hi = eval_mlp<true>(o + 0.5f, P);
                ov[e] = o;
                lv[e] = lik_from_logits(lo, hi);
            }
            __builtin_nontemporal_store(ov, o4 + i);
            __builtin_nontemporal_store(lv, l4 + i);
        }
    }
}

extern "C" void kernel_launch(void* const* d_in, const int* in_sizes, int n_in,
                              void* d_out, int out_size, void* d_ws, size_t ws_size,
                              hipStream_t stream) {
    // setup_inputs() dict order:
    // 0:x 1:noise 2:m0 3:b0 4:f0 5:m1 6:b1 7:f1 8:m2 9:b2 10:f2 11:m3 12:b3 13:quantiles
    const float* x  = (const float*)d_in[0];
    const float* nz = (const float*)d_in[1];
    const float* m0 = (const float*)d_in[2];
    const float* b0 = (const float*)d_in[3];
    const float* f0 = (const float*)d_in[4];
    const float* m1 = (const float*)d_in[5];
    const float* b1 = (const float*)d_in[6];
    const float* f1 = (const float*)d_in[7];
    const float* m2 = (const float*)d_in[8];
    const float* b2 = (const float*)d_in[9];
    const float* f2 = (const float*)d_in[10];
    const float* m3 = (const float*)d_in[11];
    const float* b3 = (const float*)d_in[12];
    const float* qq = (const float*)d_in[13];

    float* out  = (float*)d_out;
    float* lik  = out + (size_t)NCH*SPATIAL;
    float* loss = lik + (size_t)NCH*SPATIAL;

    float2* ab  = (float2*)d_ws;             // 128 * 8 B
    int*   flag = (int*)((char*)d_ws + NCH*sizeof(float2));

    eb_prep<<<1, 384, 0, stream>>>(m0,b0,f0, m1,b1,f1, m2,b2,f2, m3,b3, qq, loss, ab, flag);
    eb_main<<<GRID, THREADS, 0, stream>>>(x, nz, m0,b0,f0, m1,b1,f1, m2,b2,f2, m3,b3,
                                          ab, flag, out, lik);
}